// Round 9
// baseline (6119.736 us; speedup 1.0000x reference)
//
#include <hip/hip_runtime.h>
#include <hip/hip_bf16.h>

// Sparse 3^3 conv x2 + LayerNorm + ReLU + residual. N=400000 voxels, C=32.
// Round-8 result (first executing build): absmax=NaN => inputs are very likely
// FLOAT32 (reference dtype), since u16-misreads of f32 buffers produce NaN
// exponent patterns at ~0.4%/element. Instead of guessing, this build probes
// the dtype at runtime: g1 == ones(32), so its first 32-bit word is
//   0x3F803F80 if bf16-packed   |   0x3F800000 if float32.
// All loads + the final store branch on that (wave-uniform) flag.
// Inter-pass scratch h: bf16 at d_ws offset 0 (25.6 MB), dtype-independent.

#define NV   400000
#define KOFF 27

__device__ __forceinline__ float rb_bf2f(unsigned int u) {
    return __uint_as_float(u << 16);
}
__device__ __forceinline__ unsigned short rb_f2bf(float f) {
    unsigned int u = __float_as_uint(f);
    return (unsigned short)((u + 0x7fffu + ((u >> 16) & 1u)) >> 16);
}
__device__ __forceinline__ float ldx(const void* p, size_t i, int isbf) {
    return isbf ? rb_bf2f((unsigned int)((const unsigned short*)p)[i])
                : ((const float*)p)[i];
}

// mode 1: h   = relu(LN(conv1(x)))      reads in=x (probed dtype), writes hbuf (bf16)
// mode 2: out = relu(LN(conv2(h)) + x)  reads hbuf (bf16), resid=x, writes outp (probed dtype)
__global__ void ResidualBlock_37452114821416_kernel(
    const void* in, const int* nbr, const void* W,
    const void* gg, const void* bb, const void* resid,
    void* outp, unsigned short* hbuf, int mode)
{
    // dtype probe on gamma (= ones): exact bit patterns, wave-uniform branch.
    const int dt_bf = (((const unsigned int*)gg)[0] == 0x3F803F80u) ? 1 : 0;

    int v = blockIdx.x * blockDim.x + threadIdx.x;
    if (v >= NV) return;

    float acc[32];
    for (int c = 0; c < 32; ++c) acc[c] = 0.0f;

    for (int k = 0; k < KOFF; ++k) {
        int jn = nbr[k * NV + v];
        if (jn < 0) continue;
        const size_t fb = (size_t)jn * 32;
        const size_t wb = (size_t)k * 1024;
        for (int ci = 0; ci < 32; ++ci) {
            float xv = (mode == 2) ? rb_bf2f((unsigned int)hbuf[fb + ci])
                                   : ldx(in, fb + ci, dt_bf);
            for (int co = 0; co < 32; ++co)
                acc[co] += xv * ldx(W, wb + (size_t)ci * 32 + co, dt_bf);
        }
    }

    // Thread-local LayerNorm over the 32 channels.
    float s = 0.0f, ss = 0.0f;
    for (int c = 0; c < 32; ++c) { s += acc[c]; ss += acc[c] * acc[c]; }
    float mu  = s * (1.0f / 32.0f);
    float var = ss * (1.0f / 32.0f) - mu * mu;
    float rs  = rsqrtf(var + 1e-6f);
    for (int c = 0; c < 32; ++c)
        acc[c] = (acc[c] - mu) * rs * ldx(gg, c, dt_bf) + ldx(bb, c, dt_bf);

    if (mode == 2) {
        const size_t rb = (size_t)v * 32;
        for (int c = 0; c < 32; ++c)
            acc[c] += ldx(resid, rb + c, dt_bf);
        if (dt_bf) {
            unsigned short* orow = (unsigned short*)outp + (size_t)v * 32;
            for (int c = 0; c < 32; ++c)
                orow[c] = rb_f2bf(fmaxf(acc[c], 0.0f));
        } else {
            float* orow = (float*)outp + (size_t)v * 32;
            for (int c = 0; c < 32; ++c)
                orow[c] = fmaxf(acc[c], 0.0f);
        }
    } else {
        unsigned short* orow = hbuf + (size_t)v * 32;
        for (int c = 0; c < 32; ++c)
            orow[c] = rb_f2bf(fmaxf(acc[c], 0.0f));
    }
}

extern "C" void kernel_launch(void* const* d_in, const int* in_sizes, int n_in,
                              void* d_out, int out_size, void* d_ws, size_t ws_size,
                              hipStream_t stream)
{
    // setup_inputs() dict order: x, nbr, W1, g1, b1, W2, g2, b2
    const void* x   = d_in[0];
    const int*  nbr = (const int*)d_in[1];
    const void* W1  = d_in[2];
    const void* g1  = d_in[3];
    const void* b1  = d_in[4];
    const void* W2  = d_in[5];
    const void* g2  = d_in[6];
    const void* b2  = d_in[7];
    unsigned short* h = (unsigned short*)d_ws;   // 25.6 MB bf16 scratch

    int nblk = (NV + 255) / 256;

    // pass 1: h = relu(LN(conv1(x)))
    ResidualBlock_37452114821416_kernel<<<nblk, 256, 0, stream>>>(
        x, nbr, W1, g1, b1, x, d_out, h, 1);
    // pass 2: out = relu(LN(conv2(h)) + x)
    ResidualBlock_37452114821416_kernel<<<nblk, 256, 0, stream>>>(
        x, nbr, W2, g2, b2, x, d_out, h, 2);

    (void)in_sizes; (void)n_in; (void)out_size; (void)ws_size;
}

// Round 10
// 464.094 us; speedup vs baseline: 13.1864x; 13.1864x over previous
//
#include <hip/hip_runtime.h>
#include <hip/hip_bf16.h>

// Sparse 3^3 conv x2 + LayerNorm + ReLU + residual. N=400000, C=32, K=27.
// Contract (established round 9): ALL float inputs are FLOAT32, output f32,
// nbr int32. Inter-pass scratch h is bf16 at d_ws offset 0 (25.6 MB, proven).
// MFMA path: C=32 = one K-step of mfma_f32_16x16x32_bf16.

#define NV   400000
#define KOFF 27

typedef __bf16 bf16x8 __attribute__((ext_vector_type(8)));
typedef float  f32x4  __attribute__((ext_vector_type(4)));

union ABu { bf16x8 v; int4 i4; unsigned short us[8]; };

__device__ __forceinline__ unsigned short rb_f2bf(float f) {
    unsigned int u = __float_as_uint(f);
    return (unsigned short)((u + 0x7fffu + ((u >> 16) & 1u)) >> 16);
}

// mode 1: h(bf16) = relu(LN(conv1(x)))        gathers f32 x, writes hbuf
// mode 2: out(f32) = relu(LN(conv2(h)) + x)   gathers bf16 h, resid = x
__global__ __launch_bounds__(512, 4) void ResidualBlock_37452114821416_kernel(
    const float* __restrict__ xf,     // x [NV,32] f32 (gather src mode1, resid mode2)
    const int*   __restrict__ nbr,    // [27,NV]
    const float* __restrict__ Wf,     // [27,32,32] f32
    const float* __restrict__ gf,     // [32] f32
    const float* __restrict__ bf,     // [32] f32
    float*       __restrict__ outf,   // [NV,32] f32
    unsigned short* __restrict__ hbuf,// [NV,32] bf16 scratch
    int mode)
{
    // Per-lane MFMA B-fragments for all 27 offsets, packed bf16 in LDS:
    // Bp[k*1024 + f*512 + lane*8 + j] = W[k][cin=(lane>>4)*8+j][cout=(lane&15)+16f]
    __shared__ __align__(16) unsigned short Bp[KOFF * 1024];
    for (int e = threadIdx.x; e < KOFF * 1024; e += 512) {
        int k    = e >> 10;
        int r    = e & 1023;
        int f    = r >> 9;
        int lane = (r >> 3) & 63;
        int j    = r & 7;
        int ci   = ((lane >> 4) << 3) + j;
        int co   = (lane & 15) + (f << 4);
        Bp[e] = rb_f2bf(Wf[k * 1024 + ci * 32 + co]);
    }
    __syncthreads();

    const int lane = threadIdx.x & 63;
    const int wv   = threadIdx.x >> 6;
    const int q    = lane >> 4, n = lane & 15;
    const int i0   = blockIdx.x * 512 + wv * 64;   // 64 voxels per wave

    f32x4 acc[4][2];
    #pragma unroll
    for (int t = 0; t < 4; ++t)
        #pragma unroll
        for (int f = 0; f < 2; ++f)
            acc[t][f] = (f32x4){0.f, 0.f, 0.f, 0.f};

    for (int k = 0; k < KOFF; ++k) {
        ABu b0, b1;
        b0.i4 = *(const int4*)(Bp + k * 1024 + lane * 8);
        b1.i4 = *(const int4*)(Bp + k * 1024 + 512 + lane * 8);
        const int* nb = nbr + (size_t)k * NV;
        #pragma unroll
        for (int t = 0; t < 4; ++t) {
            int v  = i0 + t * 16 + n;              // A-row m = lane&15
            int jn = (v < NV) ? nb[v] : -1;
            if (__ballot(jn >= 0) == 0ull) continue;   // wave-uniform tile skip
            ABu a;
            a.i4 = make_int4(0, 0, 0, 0);
            if (jn >= 0) {
                if (mode == 2) {
                    a.i4 = *(const int4*)(hbuf + (size_t)jn * 32 + q * 8);
                } else {
                    const float* src = xf + (size_t)jn * 32 + q * 8;
                    float4 p0 = *(const float4*)(src);
                    float4 p1 = *(const float4*)(src + 4);
                    a.us[0] = rb_f2bf(p0.x); a.us[1] = rb_f2bf(p0.y);
                    a.us[2] = rb_f2bf(p0.z); a.us[3] = rb_f2bf(p0.w);
                    a.us[4] = rb_f2bf(p1.x); a.us[5] = rb_f2bf(p1.y);
                    a.us[6] = rb_f2bf(p1.z); a.us[7] = rb_f2bf(p1.w);
                }
            }
            acc[t][0] = __builtin_amdgcn_mfma_f32_16x16x32_bf16(a.v, b0.v, acc[t][0], 0, 0, 0);
            acc[t][1] = __builtin_amdgcn_mfma_f32_16x16x32_bf16(a.v, b1.v, acc[t][1], 0, 0, 0);
        }
    }

    // Epilogue. C/D layout: cout = lane&15 (+16 frag1), voxel row = q*4 + reg.
    const float gv0 = gf[n], gv1 = gf[n + 16];
    const float bv0 = bf[n], bv1 = bf[n + 16];
    #pragma unroll
    for (int t = 0; t < 4; ++t) {
        #pragma unroll
        for (int r = 0; r < 4; ++r) {
            float x0 = acc[t][0][r], x1 = acc[t][1][r];
            float s  = x0 + x1;
            float ss = x0 * x0 + x1 * x1;
            #pragma unroll
            for (int mm = 1; mm <= 8; mm <<= 1) {   // LN reduce over 16-lane n-group
                s  += __shfl_xor(s, mm);
                ss += __shfl_xor(ss, mm);
            }
            float mu  = s * (1.f / 32.f);
            float var = ss * (1.f / 32.f) - mu * mu;
            float rs  = rsqrtf(var + 1e-6f);
            int v = i0 + t * 16 + q * 4 + r;
            if (v < NV) {
                float y0 = (x0 - mu) * rs * gv0 + bv0;
                float y1 = (x1 - mu) * rs * gv1 + bv1;
                if (mode == 2) {
                    y0 += xf[(size_t)v * 32 + n];
                    y1 += xf[(size_t)v * 32 + n + 16];
                    outf[(size_t)v * 32 + n]      = fmaxf(y0, 0.f);
                    outf[(size_t)v * 32 + n + 16] = fmaxf(y1, 0.f);
                } else {
                    hbuf[(size_t)v * 32 + n]      = rb_f2bf(fmaxf(y0, 0.f));
                    hbuf[(size_t)v * 32 + n + 16] = rb_f2bf(fmaxf(y1, 0.f));
                }
            }
        }
    }
}

extern "C" void kernel_launch(void* const* d_in, const int* in_sizes, int n_in,
                              void* d_out, int out_size, void* d_ws, size_t ws_size,
                              hipStream_t stream)
{
    // setup_inputs() dict order: x, nbr, W1, g1, b1, W2, g2, b2 — all f32 except nbr
    const float* x   = (const float*)d_in[0];
    const int*   nbr = (const int*)d_in[1];
    const float* W1  = (const float*)d_in[2];
    const float* g1  = (const float*)d_in[3];
    const float* b1  = (const float*)d_in[4];
    const float* W2  = (const float*)d_in[5];
    const float* g2  = (const float*)d_in[6];
    const float* b2  = (const float*)d_in[7];
    float* out = (float*)d_out;
    unsigned short* h = (unsigned short*)d_ws;   // 25.6 MB bf16 scratch (proven)

    const int nblk = (NV + 511) / 512;   // 782 blocks x 8 waves x 64 voxels

    // pass 1: h = relu(LN(conv1(x)))
    ResidualBlock_37452114821416_kernel<<<nblk, 512, 0, stream>>>(
        x, nbr, W1, g1, b1, out, h, 1);
    // pass 2: out = relu(LN(conv2(h)) + x)
    ResidualBlock_37452114821416_kernel<<<nblk, 512, 0, stream>>>(
        x, nbr, W2, g2, b2, out, h, 2);

    (void)in_sizes; (void)n_in; (void)out_size; (void)ws_size;
}